// Round 1
// baseline (11840.927 us; speedup 1.0000x reference)
//
#include <hip/hip_runtime.h>
#include <math.h>

#define BB 64
#define TT 1024
#define II 256
#define HD 256

// ---------------------------------------------------------------------------
// Kernel 1: fused input projection GEMM.
//   X:[B*T, 256] @ W_g:[256,256] + b_g  ->  ws[B][T][768] (g-major: z|r|h)
// 64x64 output tile per block, BK=32, 256 threads, 4x4 micro-tile/thread.
// ---------------------------------------------------------------------------
__global__ __launch_bounds__(256) void proj_kernel(
    const float* __restrict__ X,
    const float* __restrict__ Wz, const float* __restrict__ Wr,
    const float* __restrict__ Wh,
    const float* __restrict__ bz, const float* __restrict__ br,
    const float* __restrict__ bh,
    float* __restrict__ out)  // [65536][768]
{
    __shared__ float As[64][36];  // pad 32->36: keeps float4 16B-aligned, 2-way max
    __shared__ float Bs[32][64];

    const int tid  = threadIdx.x;
    const int tx   = tid & 15;   // 0..15 -> 4 cols each
    const int ty   = tid >> 4;   // 0..15 -> 4 rows each
    const int m0   = blockIdx.x * 64;
    const int g    = blockIdx.y >> 2;          // 0:z 1:r 2:h
    const int col0 = (blockIdx.y & 3) * 64;

    const float* W    = (g == 0) ? Wz : (g == 1) ? Wr : Wh;
    const float* bias = (g == 0) ? bz : (g == 1) ? br : bh;

    float acc[4][4];
#pragma unroll
    for (int i = 0; i < 4; ++i)
#pragma unroll
        for (int j = 0; j < 4; ++j) acc[i][j] = 0.f;

    for (int k0 = 0; k0 < II; k0 += 32) {
        // stage A tile: 64 rows x 32 k  (512 float4, 2 per thread)
        int fi = tid;
#pragma unroll
        for (int rp = 0; rp < 2; ++rp, fi += 256) {
            const int row = fi >> 3;
            const int fc  = fi & 7;
            const float4 v = *reinterpret_cast<const float4*>(
                X + (size_t)(m0 + row) * II + k0 + fc * 4);
            *reinterpret_cast<float4*>(&As[row][fc * 4]) = v;
        }
        // stage B tile: 32 k x 64 cols
        fi = tid;
#pragma unroll
        for (int rp = 0; rp < 2; ++rp, fi += 256) {
            const int row = fi >> 4;
            const int fc  = fi & 15;
            const float4 v = *reinterpret_cast<const float4*>(
                W + (size_t)(k0 + row) * HD + col0 + fc * 4);
            *reinterpret_cast<float4*>(&Bs[row][fc * 4]) = v;
        }
        __syncthreads();

#pragma unroll
        for (int kk = 0; kk < 32; ++kk) {
            const float a0 = As[ty * 4 + 0][kk];
            const float a1 = As[ty * 4 + 1][kk];
            const float a2 = As[ty * 4 + 2][kk];
            const float a3 = As[ty * 4 + 3][kk];
            const float4 bv = *reinterpret_cast<const float4*>(&Bs[kk][tx * 4]);
            acc[0][0] += a0 * bv.x; acc[0][1] += a0 * bv.y;
            acc[0][2] += a0 * bv.z; acc[0][3] += a0 * bv.w;
            acc[1][0] += a1 * bv.x; acc[1][1] += a1 * bv.y;
            acc[1][2] += a1 * bv.z; acc[1][3] += a1 * bv.w;
            acc[2][0] += a2 * bv.x; acc[2][1] += a2 * bv.y;
            acc[2][2] += a2 * bv.z; acc[2][3] += a2 * bv.w;
            acc[3][0] += a3 * bv.x; acc[3][1] += a3 * bv.y;
            acc[3][2] += a3 * bv.z; acc[3][3] += a3 * bv.w;
        }
        __syncthreads();
    }

    const float4 bia = *reinterpret_cast<const float4*>(bias + col0 + tx * 4);
#pragma unroll
    for (int i = 0; i < 4; ++i) {
        float4 o;
        o.x = acc[i][0] + bia.x;
        o.y = acc[i][1] + bia.y;
        o.z = acc[i][2] + bia.z;
        o.w = acc[i][3] + bia.w;
        *reinterpret_cast<float4*>(
            out + (size_t)(m0 + ty * 4 + i) * 768 + g * 256 + col0 + tx * 4) = o;
    }
}

// ---------------------------------------------------------------------------
// Kernel 2: sequential GRU recurrence. One workgroup per batch element.
// 256 threads; thread j owns hidden column j. H lives in LDS. Weights are
// streamed from L2 (768 KB fp32, fully L2-resident). 2 barriers per step.
// ---------------------------------------------------------------------------
__global__ __launch_bounds__(256) void gru_recur(
    const float* __restrict__ xzrh,  // [B][T][768]
    const float* __restrict__ Whz, const float* __restrict__ Whr,
    const float* __restrict__ Whh,
    float* __restrict__ out)  // [B][T][256] then H_last [B][256]
{
    __shared__ float h[HD];
    __shared__ float rh[HD];

    const int b = blockIdx.x;
    const int j = threadIdx.x;

    h[j] = 0.f;
    __syncthreads();

    const float* xp = xzrh + (size_t)b * TT * 768;
    const float* wz = Whz + j;
    const float* wr = Whr + j;
    const float* wh = Whh + j;
    float* ob = out + (size_t)b * TT * HD;

    for (int t = 0; t < TT; ++t) {
        const float* xt = xp + t * 768;
        float zacc = xt[j];
        float racc = xt[256 + j];
        const float xh = xt[512 + j];

#pragma unroll 8
        for (int k = 0; k < HD; ++k) {
            const float hk = h[k];
            zacc += hk * wz[k * HD];
            racc += hk * wr[k * HD];
        }

        const float z = 1.f / (1.f + __expf(-zacc));
        const float r = 1.f / (1.f + __expf(-racc));

        rh[j] = r * h[j];
        __syncthreads();  // rh complete before second matvec

        float hacc = xh;
#pragma unroll 8
        for (int k = 0; k < HD; ++k) {
            hacc += rh[k] * wh[k * HD];
        }

        const float ht   = tanhf(hacc);
        const float hnew = z * h[j] + (1.f - z) * ht;
        ob[t * HD + j]   = hnew;

        h[j] = hnew;      // only thread j reads h[j] past the rh barrier
        __syncthreads();  // all h writes visible before next step's matvec
    }

    // H_last
    out[(size_t)BB * TT * HD + b * HD + j] = h[j];
}

// ---------------------------------------------------------------------------
extern "C" void kernel_launch(void* const* d_in, const int* in_sizes, int n_in,
                              void* d_out, int out_size, void* d_ws, size_t ws_size,
                              hipStream_t stream) {
    const float* X   = (const float*)d_in[0];
    const float* Wxz = (const float*)d_in[1];
    const float* Whz = (const float*)d_in[2];
    const float* bz  = (const float*)d_in[3];
    const float* Wxr = (const float*)d_in[4];
    const float* Whr = (const float*)d_in[5];
    const float* br  = (const float*)d_in[6];
    const float* Wxh = (const float*)d_in[7];
    const float* Whh = (const float*)d_in[8];
    const float* bh  = (const float*)d_in[9];
    float* out = (float*)d_out;
    float* ws  = (float*)d_ws;  // xzrh: [B][T][768] fp32 = 192 MiB

    proj_kernel<<<dim3(1024, 12), 256, 0, stream>>>(X, Wxz, Wxr, Wxh, bz, br, bh, ws);
    gru_recur<<<dim3(64), 256, 0, stream>>>(ws, Whz, Whr, Whh, out);
}

// Round 2
// 2083.674 us; speedup vs baseline: 5.6827x; 5.6827x over previous
//
#include <hip/hip_runtime.h>
#include <math.h>

#define BB 64
#define TT 1024
#define II 256
#define HD 256

typedef unsigned short ushort_t;
typedef unsigned int uint_t;

// ---- bf16 helpers (manual, RNE) -------------------------------------------
__device__ __forceinline__ ushort_t f2bf(float f) {
    uint_t u = __float_as_uint(f);
    uint_t r = (u + 0x7fffu + ((u >> 16) & 1u)) >> 16;
    return (ushort_t)r;
}
__device__ __forceinline__ float bf2f(ushort_t v) {
    return __uint_as_float(((uint_t)v) << 16);
}

// packed-pair bf16 dot: acc += w.lo*h.lo + w.hi*h.hi
typedef __bf16 v2bf __attribute__((ext_vector_type(2)));
__device__ __forceinline__ float dot2bf(uint_t w, uint_t h, float acc) {
#if __has_builtin(__builtin_amdgcn_fdot2_f32_bf16)
    return __builtin_amdgcn_fdot2_f32_bf16(__builtin_bit_cast(v2bf, w),
                                           __builtin_bit_cast(v2bf, h), acc, false);
#else
    acc += __uint_as_float(w << 16) * __uint_as_float(h << 16);
    acc += __uint_as_float(w & 0xffff0000u) * __uint_as_float(h & 0xffff0000u);
    return acc;
#endif
}

// ---------------------------------------------------------------------------
// Kernel 0: prepack recurrent weights fp32[256][256] -> bf16 k-pair-packed
// packed[p*256 + j] = (bf16(W[2p+1][j]) << 16) | bf16(W[2p][j]),  p in [0,128)
// ---------------------------------------------------------------------------
__global__ __launch_bounds__(256) void prepack_kernel(
    const float* __restrict__ Wz, const float* __restrict__ Wr,
    const float* __restrict__ Wh,
    uint_t* __restrict__ Pz, uint_t* __restrict__ Pr, uint_t* __restrict__ Ph)
{
    const int idx = blockIdx.x * 256 + threadIdx.x;  // 0..32767
    const int p = idx >> 8;
    const int j = idx & 255;
    const float* W = (blockIdx.y == 0) ? Wz : (blockIdx.y == 1) ? Wr : Wh;
    uint_t* P = (blockIdx.y == 0) ? Pz : (blockIdx.y == 1) ? Pr : Ph;
    const ushort_t lo = f2bf(W[(2 * p) * HD + j]);
    const ushort_t hi = f2bf(W[(2 * p + 1) * HD + j]);
    P[idx] = ((uint_t)hi << 16) | lo;
}

// ---------------------------------------------------------------------------
// Kernel 1: input projection GEMM -> bf16 ws[B][T][768]
// ---------------------------------------------------------------------------
__global__ __launch_bounds__(256) void proj_kernel(
    const float* __restrict__ X,
    const float* __restrict__ Wz, const float* __restrict__ Wr,
    const float* __restrict__ Wh,
    const float* __restrict__ bz, const float* __restrict__ br,
    const float* __restrict__ bh,
    ushort_t* __restrict__ out)  // [65536][768] bf16
{
    __shared__ float As[64][36];
    __shared__ float Bs[32][64];

    const int tid  = threadIdx.x;
    const int tx   = tid & 15;
    const int ty   = tid >> 4;
    const int m0   = blockIdx.x * 64;
    const int g    = blockIdx.y >> 2;
    const int col0 = (blockIdx.y & 3) * 64;

    const float* W    = (g == 0) ? Wz : (g == 1) ? Wr : Wh;
    const float* bias = (g == 0) ? bz : (g == 1) ? br : bh;

    float acc[4][4];
#pragma unroll
    for (int i = 0; i < 4; ++i)
#pragma unroll
        for (int j = 0; j < 4; ++j) acc[i][j] = 0.f;

    for (int k0 = 0; k0 < II; k0 += 32) {
        int fi = tid;
#pragma unroll
        for (int rp = 0; rp < 2; ++rp, fi += 256) {
            const int row = fi >> 3;
            const int fc  = fi & 7;
            const float4 v = *reinterpret_cast<const float4*>(
                X + (size_t)(m0 + row) * II + k0 + fc * 4);
            *reinterpret_cast<float4*>(&As[row][fc * 4]) = v;
        }
        fi = tid;
#pragma unroll
        for (int rp = 0; rp < 2; ++rp, fi += 256) {
            const int row = fi >> 4;
            const int fc  = fi & 15;
            const float4 v = *reinterpret_cast<const float4*>(
                W + (size_t)(k0 + row) * HD + col0 + fc * 4);
            *reinterpret_cast<float4*>(&Bs[row][fc * 4]) = v;
        }
        __syncthreads();

#pragma unroll
        for (int kk = 0; kk < 32; ++kk) {
            const float a0 = As[ty * 4 + 0][kk];
            const float a1 = As[ty * 4 + 1][kk];
            const float a2 = As[ty * 4 + 2][kk];
            const float a3 = As[ty * 4 + 3][kk];
            const float4 bv = *reinterpret_cast<const float4*>(&Bs[kk][tx * 4]);
            acc[0][0] += a0 * bv.x; acc[0][1] += a0 * bv.y;
            acc[0][2] += a0 * bv.z; acc[0][3] += a0 * bv.w;
            acc[1][0] += a1 * bv.x; acc[1][1] += a1 * bv.y;
            acc[1][2] += a1 * bv.z; acc[1][3] += a1 * bv.w;
            acc[2][0] += a2 * bv.x; acc[2][1] += a2 * bv.y;
            acc[2][2] += a2 * bv.z; acc[2][3] += a2 * bv.w;
            acc[3][0] += a3 * bv.x; acc[3][1] += a3 * bv.y;
            acc[3][2] += a3 * bv.z; acc[3][3] += a3 * bv.w;
        }
        __syncthreads();
    }

    const float4 bia = *reinterpret_cast<const float4*>(bias + col0 + tx * 4);
#pragma unroll
    for (int i = 0; i < 4; ++i) {
        ushort4 o;
        o.x = f2bf(acc[i][0] + bia.x);
        o.y = f2bf(acc[i][1] + bia.y);
        o.z = f2bf(acc[i][2] + bia.z);
        o.w = f2bf(acc[i][3] + bia.w);
        *reinterpret_cast<ushort4*>(
            out + (size_t)(m0 + ty * 4 + i) * 768 + g * 256 + col0 + tx * 4) = o;
    }
}

// ---------------------------------------------------------------------------
// Kernel 2: recurrence. 64 blocks (1/batch) x 1024 threads (16 waves).
// thread = (column j = tid&255, K-quarter kq = tid>>8).
// W_hz/W_hr: bf16 pair-packed in VGPRs (loaded once). W_hh: streamed from L2.
// h / r*h: packed bf16 in LDS; fp32 h kept in-register for gating/output.
// ---------------------------------------------------------------------------
__global__ __launch_bounds__(1024) void gru_recur(
    const ushort_t* __restrict__ xzrh,  // [B][T][768] bf16
    const uint_t* __restrict__ Pz, const uint_t* __restrict__ Pr,
    const uint_t* __restrict__ Ph,
    float* __restrict__ out)  // [B][T][256] then H_last [B][256]
{
    __shared__ uint_t hp[128];    // h as bf16 pairs
    __shared__ uint_t rhp[128];   // r*h as bf16 pairs
    __shared__ float pz[4][256];
    __shared__ float pr[4][256];
    __shared__ float phh[4][256];

    const int tid = threadIdx.x;
    const int j   = tid & 255;
    const int kq  = tid >> 8;   // 0..3 (wave-uniform: wave w has kq = w>>2)
    const int b   = blockIdx.x;

    // preload z/r weight columns into registers: 32 packed pairs each
    uint_t wz[32], wr[32];
    {
        const uint_t* zp = Pz + (size_t)(kq * 32) * HD + j;
        const uint_t* rp = Pr + (size_t)(kq * 32) * HD + j;
#pragma unroll
        for (int i = 0; i < 32; ++i) { wz[i] = zp[(size_t)i * HD]; }
#pragma unroll
        for (int i = 0; i < 32; ++i) { wr[i] = rp[(size_t)i * HD]; }
    }
    const uint_t* hwp = Ph + (size_t)(kq * 32) * HD + j;

    float hj = 0.f;
    if (tid < 128) hp[tid] = 0u;   // waves 0,1 — wave-uniform branch
    __syncthreads();

    const ushort_t* xp = xzrh + (size_t)b * TT * 768;
    float* ob = out + (size_t)b * TT * HD;

    for (int t = 0; t < TT; ++t) {
        const ushort_t* xt = xp + t * 768;
        // issue x loads early; consumed after the first barrier
        const float xz = bf2f(xt[j]);
        const float xr = bf2f(xt[256 + j]);
        const float xh = bf2f(xt[512 + j]);

        // ---- phase 1: z,r partial dot over this thread's 64 k's ----
        float az = 0.f, ar = 0.f;
        {
            const uint_t* hq = &hp[kq * 32];
#pragma unroll
            for (int i = 0; i < 8; ++i) {
                const uint4 hv = *reinterpret_cast<const uint4*>(&hq[i * 4]);
                az = dot2bf(wz[4 * i + 0], hv.x, az);
                az = dot2bf(wz[4 * i + 1], hv.y, az);
                az = dot2bf(wz[4 * i + 2], hv.z, az);
                az = dot2bf(wz[4 * i + 3], hv.w, az);
                ar = dot2bf(wr[4 * i + 0], hv.x, ar);
                ar = dot2bf(wr[4 * i + 1], hv.y, ar);
                ar = dot2bf(wr[4 * i + 2], hv.z, ar);
                ar = dot2bf(wr[4 * i + 3], hv.w, ar);
            }
        }
        pz[kq][j] = az;
        pr[kq][j] = ar;
        __syncthreads();

        // ---- combine z,r (duplicated across all waves; no divergence) ----
        const float zs = xz + pz[0][j] + pz[1][j] + pz[2][j] + pz[3][j];
        const float rs = xr + pr[0][j] + pr[1][j] + pr[2][j] + pr[3][j];
        const float z  = 1.f / (1.f + __expf(-zs));
        const float r  = 1.f / (1.f + __expf(-rs));
        const float rh = r * hj;
        reinterpret_cast<ushort_t*>(rhp)[j] = f2bf(rh);  // 4x same-value dup write
        __syncthreads();

        // ---- phase 2: h~ partial dot (W_hh streamed from L2) ----
        float ah = 0.f;
        {
            const uint_t* rq = &rhp[kq * 32];
#pragma unroll
            for (int i = 0; i < 8; ++i) {
                const uint4 rv = *reinterpret_cast<const uint4*>(&rq[i * 4]);
                const uint_t w0 = hwp[(size_t)(4 * i + 0) * HD];
                const uint_t w1 = hwp[(size_t)(4 * i + 1) * HD];
                const uint_t w2 = hwp[(size_t)(4 * i + 2) * HD];
                const uint_t w3 = hwp[(size_t)(4 * i + 3) * HD];
                ah = dot2bf(w0, rv.x, ah);
                ah = dot2bf(w1, rv.y, ah);
                ah = dot2bf(w2, rv.z, ah);
                ah = dot2bf(w3, rv.w, ah);
            }
        }
        phh[kq][j] = ah;
        __syncthreads();

        // ---- combine h~ and update (duplicated across waves) ----
        const float hs = xh + phh[0][j] + phh[1][j] + phh[2][j] + phh[3][j];
        const float e  = __expf(2.f * hs);
        const float th = 1.f - 2.f / (e + 1.f);   // tanh(hs)
        const float hnew = z * hj + (1.f - z) * th;
        hj = hnew;
        if (kq == 0) ob[t * HD + j] = hnew;       // wave-uniform predicate
        reinterpret_cast<ushort_t*>(hp)[j] = f2bf(hnew);
        __syncthreads();
    }

    if (kq == 0) out[(size_t)BB * TT * HD + b * HD + j] = hj;
}

// ---------------------------------------------------------------------------
extern "C" void kernel_launch(void* const* d_in, const int* in_sizes, int n_in,
                              void* d_out, int out_size, void* d_ws, size_t ws_size,
                              hipStream_t stream) {
    const float* X   = (const float*)d_in[0];
    const float* Wxz = (const float*)d_in[1];
    const float* Whz = (const float*)d_in[2];
    const float* bz  = (const float*)d_in[3];
    const float* Wxr = (const float*)d_in[4];
    const float* Whr = (const float*)d_in[5];
    const float* br  = (const float*)d_in[6];
    const float* Wxh = (const float*)d_in[7];
    const float* Whh = (const float*)d_in[8];
    const float* bh  = (const float*)d_in[9];
    float* out = (float*)d_out;

    // ws layout: [0, 96 MiB) xzrh bf16; then 3 x 128 KiB packed weights
    ushort_t* xzrh = (ushort_t*)d_ws;
    uint_t* Pz = (uint_t*)((char*)d_ws + (size_t)BB * TT * 768 * 2);
    uint_t* Pr = Pz + 128 * HD;
    uint_t* Ph = Pr + 128 * HD;

    prepack_kernel<<<dim3(128, 3), 256, 0, stream>>>(Whz, Whr, Whh, Pz, Pr, Ph);
    proj_kernel<<<dim3(1024, 12), 256, 0, stream>>>(X, Wxz, Wxr, Wxh, bz, br, bh, xzrh);
    gru_recur<<<dim3(64), 1024, 0, stream>>>(xzrh, Pz, Pr, Ph, out);
}

// Round 6
// 2057.179 us; speedup vs baseline: 5.7559x; 1.0129x over previous
//
#include <hip/hip_runtime.h>
#include <math.h>

#define BB 64
#define TT 1024
#define II 256
#define HD 256

typedef unsigned short ushort_t;
typedef unsigned int uint_t;

// ---- bf16 helpers (manual, RNE) -------------------------------------------
__device__ __forceinline__ ushort_t f2bf(float f) {
    uint_t u = __float_as_uint(f);
    uint_t r = (u + 0x7fffu + ((u >> 16) & 1u)) >> 16;
    return (ushort_t)r;
}
__device__ __forceinline__ float bf2f(ushort_t v) {
    return __uint_as_float(((uint_t)v) << 16);
}

// packed-pair bf16 dot: acc += w.lo*h.lo + w.hi*h.hi
typedef __bf16 v2bf __attribute__((ext_vector_type(2)));
__device__ __forceinline__ float dot2bf(uint_t w, uint_t h, float acc) {
#if __has_builtin(__builtin_amdgcn_fdot2_f32_bf16)
    return __builtin_amdgcn_fdot2_f32_bf16(__builtin_bit_cast(v2bf, w),
                                           __builtin_bit_cast(v2bf, h), acc, false);
#else
    acc += __uint_as_float(w << 16) * __uint_as_float(h << 16);
    acc += __uint_as_float(w & 0xffff0000u) * __uint_as_float(h & 0xffff0000u);
    return acc;
#endif
}

__device__ __forceinline__ float fast_rcp(float x) {
#if __has_builtin(__builtin_amdgcn_rcpf)
    return __builtin_amdgcn_rcpf(x);
#else
    return 1.f / x;
#endif
}
__device__ __forceinline__ float sigm(float x) {
    return fast_rcp(1.f + __expf(-x));
}
__device__ __forceinline__ float tanh_fast(float x) {
    // 1 - 2/(1+e^{2x}); saturates correctly at +-1
    return 1.f - 2.f * fast_rcp(1.f + __expf(2.f * x));
}

// ---------------------------------------------------------------------------
// Kernel 0: prepack recurrent weights fp32[256][256] -> bf16 k-pair-packed
// packed[p*256 + j] = (bf16(W[2p+1][j]) << 16) | bf16(W[2p][j]),  p in [0,128)
// ---------------------------------------------------------------------------
__global__ __launch_bounds__(256) void prepack_kernel(
    const float* __restrict__ Wz, const float* __restrict__ Wr,
    const float* __restrict__ Wh,
    uint_t* __restrict__ Pz, uint_t* __restrict__ Pr, uint_t* __restrict__ Ph)
{
    const int idx = blockIdx.x * 256 + threadIdx.x;  // 0..32767
    const int p = idx >> 8;
    const int j = idx & 255;
    const float* W = (blockIdx.y == 0) ? Wz : (blockIdx.y == 1) ? Wr : Wh;
    uint_t* P = (blockIdx.y == 0) ? Pz : (blockIdx.y == 1) ? Pr : Ph;
    const ushort_t lo = f2bf(W[(2 * p) * HD + j]);
    const ushort_t hi = f2bf(W[(2 * p + 1) * HD + j]);
    P[idx] = ((uint_t)hi << 16) | lo;
}

// ---------------------------------------------------------------------------
// Kernel 1: input projection GEMM -> bf16 ws[B][T][768]
// ---------------------------------------------------------------------------
__global__ __launch_bounds__(256) void proj_kernel(
    const float* __restrict__ X,
    const float* __restrict__ Wz, const float* __restrict__ Wr,
    const float* __restrict__ Wh,
    const float* __restrict__ bz, const float* __restrict__ br,
    const float* __restrict__ bh,
    ushort_t* __restrict__ out)  // [65536][768] bf16
{
    __shared__ float As[64][36];
    __shared__ float Bs[32][64];

    const int tid  = threadIdx.x;
    const int tx   = tid & 15;
    const int ty   = tid >> 4;
    const int m0   = blockIdx.x * 64;
    const int g    = blockIdx.y >> 2;
    const int col0 = (blockIdx.y & 3) * 64;

    const float* W    = (g == 0) ? Wz : (g == 1) ? Wr : Wh;
    const float* bias = (g == 0) ? bz : (g == 1) ? br : bh;

    float acc[4][4];
#pragma unroll
    for (int i = 0; i < 4; ++i)
#pragma unroll
        for (int j = 0; j < 4; ++j) acc[i][j] = 0.f;

    for (int k0 = 0; k0 < II; k0 += 32) {
        int fi = tid;
#pragma unroll
        for (int rp = 0; rp < 2; ++rp, fi += 256) {
            const int row = fi >> 3;
            const int fc  = fi & 7;
            const float4 v = *reinterpret_cast<const float4*>(
                X + (size_t)(m0 + row) * II + k0 + fc * 4);
            *reinterpret_cast<float4*>(&As[row][fc * 4]) = v;
        }
        fi = tid;
#pragma unroll
        for (int rp = 0; rp < 2; ++rp, fi += 256) {
            const int row = fi >> 4;
            const int fc  = fi & 15;
            const float4 v = *reinterpret_cast<const float4*>(
                W + (size_t)(k0 + row) * HD + col0 + fc * 4);
            *reinterpret_cast<float4*>(&Bs[row][fc * 4]) = v;
        }
        __syncthreads();

#pragma unroll
        for (int kk = 0; kk < 32; ++kk) {
            const float a0 = As[ty * 4 + 0][kk];
            const float a1 = As[ty * 4 + 1][kk];
            const float a2 = As[ty * 4 + 2][kk];
            const float a3 = As[ty * 4 + 3][kk];
            const float4 bv = *reinterpret_cast<const float4*>(&Bs[kk][tx * 4]);
            acc[0][0] += a0 * bv.x; acc[0][1] += a0 * bv.y;
            acc[0][2] += a0 * bv.z; acc[0][3] += a0 * bv.w;
            acc[1][0] += a1 * bv.x; acc[1][1] += a1 * bv.y;
            acc[1][2] += a1 * bv.z; acc[1][3] += a1 * bv.w;
            acc[2][0] += a2 * bv.x; acc[2][1] += a2 * bv.y;
            acc[2][2] += a2 * bv.z; acc[2][3] += a2 * bv.w;
            acc[3][0] += a3 * bv.x; acc[3][1] += a3 * bv.y;
            acc[3][2] += a3 * bv.z; acc[3][3] += a3 * bv.w;
        }
        __syncthreads();
    }

    const float4 bia = *reinterpret_cast<const float4*>(bias + col0 + tx * 4);
#pragma unroll
    for (int i = 0; i < 4; ++i) {
        ushort4 o;
        o.x = f2bf(acc[i][0] + bia.x);
        o.y = f2bf(acc[i][1] + bia.y);
        o.z = f2bf(acc[i][2] + bia.z);
        o.w = f2bf(acc[i][3] + bia.w);
        *reinterpret_cast<ushort4*>(
            out + (size_t)(m0 + ty * 4 + i) * 768 + g * 256 + col0 + tx * 4) = o;
    }
}

// ---------------------------------------------------------------------------
// Kernel 2: recurrence. 64 blocks (1/batch) x 1024 threads (16 waves).
// lane = 4*j' + kq: column j = wave*16 + (lane>>2), k-quarter kq = lane&3.
// ALL three recurrent weight matrices live in VGPRs (96 regs/thread).
// kq-reduction via shfl_xor inside the 4-lane group -> 2 barriers/step.
// h and r*h round-trip through a tiny padded LDS array (conflict-free).
// x[t] is loaded at the TOP of each step and consumed within the step —
// no cross-iteration prefetch registers (minimizes live ranges; correct by
// construction after the round-3 rotation bug).
// ---------------------------------------------------------------------------
#define SLAB 36  // uints per kq slab: 32 data + 4 pad (bank-shifts the streams)

// padded u16 index for column j: slab (j>>6), within-slab u16 (j&63)
#define PU16(j) (((j) >> 6) * (SLAB * 2) + ((j) & 63))

__global__ __launch_bounds__(1024) void gru_recur(
    const ushort_t* __restrict__ xzrh,  // [B][T][768] bf16
    const uint_t* __restrict__ Pz, const uint_t* __restrict__ Pr,
    const uint_t* __restrict__ Ph,
    float* __restrict__ out)  // [B][T][256] then H_last [B][256]
{
    __shared__ __align__(16) uint_t hp[4 * SLAB];
    __shared__ __align__(16) uint_t rhp[4 * SLAB];

    const int tid  = threadIdx.x;
    const int lane = tid & 63;
    const int w    = tid >> 6;            // wave 0..15
    const int kq   = lane & 3;            // k-quarter within 4-lane group
    const int j    = w * 16 + (lane >> 2);  // hidden column 0..255
    const int b    = blockIdx.x;

    // ---- preload all weights into VGPRs: 32 packed k-pairs per matrix ----
    uint_t wz[32], wr[32], wh[32];
    {
        const size_t base = (size_t)(kq * 32) * HD + j;
#pragma unroll
        for (int i = 0; i < 32; ++i) wz[i] = Pz[base + (size_t)i * HD];
#pragma unroll
        for (int i = 0; i < 32; ++i) wr[i] = Pr[base + (size_t)i * HD];
#pragma unroll
        for (int i = 0; i < 32; ++i) wh[i] = Ph[base + (size_t)i * HD];
    }

    float hj = 0.f;
    if (tid < 4 * SLAB) hp[tid] = 0u;
    __syncthreads();

    const ushort_t* xp = xzrh + (size_t)b * TT * 768;
    float* ob = out + (size_t)b * TT * HD;

    const uint_t* hq  = &hp[kq * SLAB];
    const uint_t* rq  = &rhp[kq * SLAB];

    for (int t = 0; t < TT; ++t) {
        // x[t]: loaded at step top, consumed after phase-1 dot (z,r) and
        // after phase-2 dot (h~). ~200+ cycles of VALU slack before first use.
        const ushort_t* xt = xp + (size_t)t * 768;
        const float xz_r = bf2f(xt[j]);
        const float xr_r = bf2f(xt[256 + j]);
        const float xh_r = bf2f(xt[512 + j]);

        // ---- phase 1: z,r dot over this thread's 64 k's (32 pairs) ----
        float az = 0.f, ar = 0.f;
#pragma unroll
        for (int i = 0; i < 8; ++i) {
            const uint4 hv = *reinterpret_cast<const uint4*>(&hq[i * 4]);
            az = dot2bf(wz[4 * i + 0], hv.x, az);
            ar = dot2bf(wr[4 * i + 0], hv.x, ar);
            az = dot2bf(wz[4 * i + 1], hv.y, az);
            ar = dot2bf(wr[4 * i + 1], hv.y, ar);
            az = dot2bf(wz[4 * i + 2], hv.z, az);
            ar = dot2bf(wr[4 * i + 2], hv.z, ar);
            az = dot2bf(wz[4 * i + 3], hv.w, az);
            ar = dot2bf(wr[4 * i + 3], hv.w, ar);
        }
        // allreduce across the 4-lane kq group
        az += __shfl_xor(az, 1); az += __shfl_xor(az, 2);
        ar += __shfl_xor(ar, 1); ar += __shfl_xor(ar, 2);

        const float z  = sigm(xz_r + az);
        const float r  = sigm(xr_r + ar);
        const float rh = r * hj;
        if (kq == 0) reinterpret_cast<ushort_t*>(rhp)[PU16(j)] = f2bf(rh);
        __syncthreads();

        // ---- phase 2: h~ dot ----
        float ah0 = 0.f, ah1 = 0.f;
#pragma unroll
        for (int i = 0; i < 8; ++i) {
            const uint4 rv = *reinterpret_cast<const uint4*>(&rq[i * 4]);
            ah0 = dot2bf(wh[4 * i + 0], rv.x, ah0);
            ah1 = dot2bf(wh[4 * i + 1], rv.y, ah1);
            ah0 = dot2bf(wh[4 * i + 2], rv.z, ah0);
            ah1 = dot2bf(wh[4 * i + 3], rv.w, ah1);
        }
        float ah = ah0 + ah1;
        ah += __shfl_xor(ah, 1); ah += __shfl_xor(ah, 2);

        const float th   = tanh_fast(xh_r + ah);
        const float hnew = z * hj + (1.f - z) * th;
        hj = hnew;
        if (kq == 0) {
            reinterpret_cast<ushort_t*>(hp)[PU16(j)] = f2bf(hnew);
            ob[t * HD + j] = hnew;
        }
        __syncthreads();
    }

    if (kq == 0) out[(size_t)BB * TT * HD + b * HD + j] = hj;
}

// ---------------------------------------------------------------------------
extern "C" void kernel_launch(void* const* d_in, const int* in_sizes, int n_in,
                              void* d_out, int out_size, void* d_ws, size_t ws_size,
                              hipStream_t stream) {
    const float* X   = (const float*)d_in[0];
    const float* Wxz = (const float*)d_in[1];
    const float* Whz = (const float*)d_in[2];
    const float* bz  = (const float*)d_in[3];
    const float* Wxr = (const float*)d_in[4];
    const float* Whr = (const float*)d_in[5];
    const float* br  = (const float*)d_in[6];
    const float* Wxh = (const float*)d_in[7];
    const float* Whh = (const float*)d_in[8];
    const float* bh  = (const float*)d_in[9];
    float* out = (float*)d_out;

    // ws layout: [0, 96 MiB) xzrh bf16; then 3 x 128 KiB packed weights
    ushort_t* xzrh = (ushort_t*)d_ws;
    uint_t* Pz = (uint_t*)((char*)d_ws + (size_t)BB * TT * 768 * 2);
    uint_t* Pr = Pz + 128 * HD;
    uint_t* Ph = Pr + 128 * HD;

    prepack_kernel<<<dim3(128, 3), 256, 0, stream>>>(Whz, Whr, Whh, Pz, Pr, Ph);
    proj_kernel<<<dim3(1024, 12), 256, 0, stream>>>(X, Wxz, Wxr, Wxh, bz, br, bh, xzrh);
    gru_recur<<<dim3(64), 1024, 0, stream>>>(xzrh, Pz, Pr, Ph, out);
}